// Round 2
// 6516.730 us; speedup vs baseline: 1.8614x; 1.8614x over previous
//
#include <hip/hip_runtime.h>

// LSTM layer. Inputs f32, OUTPUT f32.
//
// Phase A (parallel GEMM): x_gates[r,:] = W_ih·x[r] + b_ih + b_hh, r = t*64+b.
//   128x128 LDS-tiled f32 GEMM, 256 threads, 8x8 micro-tile, BK=64,
//   transposed padded LDS tiles, reg-staged prefetch, 2 blocks/CU.
//   Writes xg in NATURAL layout: xg[r][g] = gate g of row r.
//
// Phase B (persistent, 256 wgs = 1/CU): same verified exchange protocol.
//   ONE FIX this round: read xg at natural column `row` (= 256*gt+64*q+u)
//   instead of the legacy permuted column (256*q+tid) that matched the old
//   persistent-W xgates. Read remains wave-coalesced (base + lane).

#define TT 2048
#define BB 64
#define HH 256
#define GG 1024  // 4H

// ws layout
#define EXCH_OFF 0         // 64 x 2 x 256 x 8B = 256 KiB
#define CST_OFF 0x40000    // 64 x 256 f32 = 64 KiB
#define XG_OFF 0x50000     // chunkT*64*1024 f32

// Phase A GEMM tile
#define BM 128
#define BN 128
#define BK 64
#define LDT 132  // padded leading dim (floats); %4==0 keeps float4 LDS reads aligned

__device__ __forceinline__ float sigm(float x) { return 1.0f / (1.0f + __expf(-x)); }
__device__ __forceinline__ float tanh_(float x) {
  float e = __expf(2.0f * x);
  return 1.0f - 2.0f / (e + 1.0f);
}

// ---------------- Phase A: x_gates (tiled f32 GEMM) ----------------
__global__ __launch_bounds__(256, 2) void lstm_xgates(
    const float* __restrict__ xin,  // [T,B,256]
    const float* __restrict__ Wih,  // [1024,256]
    const float* __restrict__ bih, const float* __restrict__ bhh,
    float* __restrict__ xg,  // [ct*64, 1024] natural layout
    int t0, int ct)
{
  const int rows = ct * BB;
  const int tid = (int)threadIdx.x;
  const int mb = (int)blockIdx.x >> 3;   // row-tile index
  const int cb = (int)blockIdx.x & 7;    // col-tile index (1024/128 = 8)
  const int row0 = mb * BM;
  const int col0 = cb * BN;

  __shared__ __align__(16) float As[BK][LDT];  // As[k][m] = X[row0+m][k0+k]
  __shared__ __align__(16) float Bs[BK][LDT];  // Bs[k][n] = W[col0+n][k0+k]

  const int sc = tid & 15;  // staging: float4 col within BK (16*4 = 64)
  const int sr = tid >> 4;  // staging: base row, step 16 (8 rows each)
  const int tm = tid >> 4;  // micro-tile row group (8 rows at 8*tm)
  const int tn = tid & 15;  // micro-tile col group (4 cols at 4*tn, 4 at 64+4*tn)

  const float* xbase = xin + (size_t)t0 * BB * HH;

  // prefetch k-tile 0 into registers
  float4 xa[8], wb[8];
#pragma unroll
  for (int i = 0; i < 8; ++i) {
    int gr = row0 + sr + 16 * i;
    int grc = gr < rows ? gr : 0;
    xa[i] = *(const float4*)(xbase + (size_t)grc * HH + 4 * sc);
    wb[i] = *(const float4*)(Wih + (size_t)(col0 + sr + 16 * i) * HH + 4 * sc);
  }

  float acc[8][8];
#pragma unroll
  for (int i = 0; i < 8; ++i)
#pragma unroll
    for (int j = 0; j < 8; ++j) acc[i][j] = 0.f;

  const int KT = HH / BK;  // 4
  for (int kt = 0; kt < KT; ++kt) {
    // staged regs -> LDS, transposed
#pragma unroll
    for (int i = 0; i < 8; ++i) {
      int r = sr + 16 * i;
      As[4 * sc + 0][r] = xa[i].x;
      As[4 * sc + 1][r] = xa[i].y;
      As[4 * sc + 2][r] = xa[i].z;
      As[4 * sc + 3][r] = xa[i].w;
      Bs[4 * sc + 0][r] = wb[i].x;
      Bs[4 * sc + 1][r] = wb[i].y;
      Bs[4 * sc + 2][r] = wb[i].z;
      Bs[4 * sc + 3][r] = wb[i].w;
    }
    __syncthreads();

    // prefetch next k-tile (latency hidden under the 64-k compute below)
    if (kt + 1 < KT) {
      const int k0 = (kt + 1) * BK;
#pragma unroll
      for (int i = 0; i < 8; ++i) {
        int gr = row0 + sr + 16 * i;
        int grc = gr < rows ? gr : 0;
        xa[i] = *(const float4*)(xbase + (size_t)grc * HH + k0 + 4 * sc);
        wb[i] = *(const float4*)(Wih + (size_t)(col0 + sr + 16 * i) * HH + k0 + 4 * sc);
      }
    }

#pragma unroll 4
    for (int k = 0; k < BK; ++k) {
      float4 a0 = *(const float4*)(&As[k][8 * tm]);       // 16-lane broadcast
      float4 a1 = *(const float4*)(&As[k][8 * tm + 4]);
      float4 b0 = *(const float4*)(&Bs[k][4 * tn]);       // 2 lanes/bank: free
      float4 b1 = *(const float4*)(&Bs[k][64 + 4 * tn]);
      const float av[8] = {a0.x, a0.y, a0.z, a0.w, a1.x, a1.y, a1.z, a1.w};
      const float bv[8] = {b0.x, b0.y, b0.z, b0.w, b1.x, b1.y, b1.z, b1.w};
#pragma unroll
      for (int i = 0; i < 8; ++i)
#pragma unroll
        for (int j = 0; j < 8; ++j)
          acc[i][j] = fmaf(av[i], bv[j], acc[i][j]);
    }
    __syncthreads();
  }

  // epilogue: bias + store. Cols: [col0+4tn .. +3] and [col0+64+4tn .. +3].
  const float4 bi0 = *(const float4*)(bih + col0 + 4 * tn);
  const float4 bh0 = *(const float4*)(bhh + col0 + 4 * tn);
  const float4 bi1 = *(const float4*)(bih + col0 + 64 + 4 * tn);
  const float4 bh1 = *(const float4*)(bhh + col0 + 64 + 4 * tn);
  const float4 bia0 = make_float4(bi0.x + bh0.x, bi0.y + bh0.y, bi0.z + bh0.z, bi0.w + bh0.w);
  const float4 bia1 = make_float4(bi1.x + bh1.x, bi1.y + bh1.y, bi1.z + bh1.z, bi1.w + bh1.w);

#pragma unroll
  for (int i = 0; i < 8; ++i) {
    int r = row0 + 8 * tm + i;
    if (r < rows) {
      float4 o0 = make_float4(acc[i][0] + bia0.x, acc[i][1] + bia0.y,
                              acc[i][2] + bia0.z, acc[i][3] + bia0.w);
      float4 o1 = make_float4(acc[i][4] + bia1.x, acc[i][5] + bia1.y,
                              acc[i][6] + bia1.z, acc[i][7] + bia1.w);
      float* op = xg + (size_t)r * GG + col0;
      *(float4*)(op + 4 * tn) = o0;
      *(float4*)(op + 64 + 4 * tn) = o1;
    }
  }
}

// ---------------- Phase B: recurrence ----------------
__global__ __launch_bounds__(256, 1) void lstm_rec(
    const float* __restrict__ h0, const float* __restrict__ c0,
    const float* __restrict__ Whh,  // [1024,256]
    const float* __restrict__ xg,   // [ct*64, 1024] natural layout
    float* __restrict__ out,        // f32: [T,B,256] ++ hT ++ cT
    unsigned long long* exch,       // [64][2][256] tagged f32
    float* __restrict__ cstate,     // [64][256]
    int t0, int t1)
{
  const int tid = threadIdx.x;
  const int w = blockIdx.x;
  // XCD-swizzle: a batch's 4 wgs share blockIdx%8 (perf heuristic only).
  const int r = w & 7, q = (w >> 3) & 3, s5 = w >> 5;
  const int b = 8 * s5 + r;  // batch 0..63
  const int gt = tid >> 6, u = tid & 63;
  const int row = 256 * gt + 64 * q + u;  // this thread's gate row AND its xg column

  float4 wv[64];
  {
    const float4* wp = (const float4*)(Whh + (size_t)row * HH);
#pragma unroll
    for (int k = 0; k < 64; ++k) wv[k] = wp[k];
  }

  float cst = 0.f;
  if (tid < 64) {
    const int jj = 64 * q + tid;
    cst = (t0 == 0) ? c0[b * HH + jj] : cstate[b * HH + jj];
  }

  __shared__ __align__(16) float hbf[256];
  __shared__ float gl[256];

  unsigned long long* exb = exch + b * 512;  // 2 parity slots x 256

  // x_gate for t0 (natural layout: column = row). Wave-coalesced: base+lane.
  float xgv = xg[(size_t)b * GG + row];

  for (int t = t0; t < t1; ++t) {
    // ---- phase 1: h_t -> LDS (f32) ----
    if (t == 0) {
      hbf[tid] = h0[b * HH + tid];
    } else {
      unsigned long long* slot = exb + ((t & 1) << 8) + tid;
      unsigned long long wd;
      do {
        wd = __hip_atomic_load(slot, __ATOMIC_RELAXED, __HIP_MEMORY_SCOPE_AGENT);
      } while ((unsigned int)(wd >> 32) != (unsigned int)t);
      union { unsigned int i; float f; } cv;
      cv.i = (unsigned int)wd;
      hbf[tid] = cv.f;
    }
    __syncthreads();

    // prefetch x_gate for t+1 (hidden under the dot loop)
    float xgn = 0.f;
    if (t + 1 < t1)
      xgn = xg[((size_t)(t + 1 - t0) * BB + b) * GG + row];

    // ---- phase 2: gate = xg + Whh[row]·h_t (f32) ----
    float a0 = xgv, a1 = 0.f, a2 = 0.f, a3 = 0.f;
    {
      const float4* hq = (const float4*)hbf;
#pragma unroll
      for (int k = 0; k < 64; ++k) {
        float4 hv = hq[k];  // same-address LDS broadcast
        a0 = fmaf(wv[k].x, hv.x, a0);
        a1 = fmaf(wv[k].y, hv.y, a1);
        a2 = fmaf(wv[k].z, hv.z, a2);
        a3 = fmaf(wv[k].w, hv.w, a3);
      }
    }
    gl[tid] = (a0 + a1) + (a2 + a3);
    xgv = xgn;
    __syncthreads();

    // ---- phase 3: elementwise + publish (threads 0..63) ----
    if (tid < 64) {
      const float gi = gl[tid];
      const float gf = gl[64 + tid];
      const float gg = gl[128 + tid];
      const float go = gl[192 + tid];
      const float ig = sigm(gi), fg = sigm(gf), gc = tanh_(gg), og = sigm(go);
      cst = fg * cst + ig * gc;
      const float hv = og * tanh_(cst);
      const int jj = 64 * q + tid;
      out[(size_t)t * (BB * HH) + (size_t)b * HH + jj] = hv;
      union { float f; unsigned int i; } hu;
      hu.f = hv;
      // tag t+1 rides with the f32 payload in one 64-bit word
      __hip_atomic_store(exb + (((t + 1) & 1) << 8) + jj,
                         (((unsigned long long)(unsigned int)(t + 1)) << 32) | hu.i,
                         __ATOMIC_RELAXED, __HIP_MEMORY_SCOPE_AGENT);
      if (t == TT - 1) {
        const size_t base = (size_t)TT * (BB * HH);
        out[base + (size_t)b * HH + jj] = hv;             // h_T
        out[base + BB * HH + (size_t)b * HH + jj] = cst;  // c_T
      }
      if (t == t1 - 1) cstate[b * HH + jj] = cst;
    }
    // gl/hbf rewrites are fenced by the next iteration's barriers.
  }
}

extern "C" void kernel_launch(void* const* d_in, const int* in_sizes, int n_in,
                              void* d_out, int out_size, void* d_ws, size_t ws_size,
                              hipStream_t stream) {
  const float* xin = (const float*)d_in[0];
  const float* h0 = (const float*)d_in[1];
  const float* c0 = (const float*)d_in[2];
  const float* Wih = (const float*)d_in[3];
  const float* Whh = (const float*)d_in[4];
  const float* bih = (const float*)d_in[5];
  const float* bhh = (const float*)d_in[6];
  float* out = (float*)d_out;

  char* ws = (char*)d_ws;
  unsigned long long* exch = (unsigned long long*)(ws + EXCH_OFF);
  float* cstate = (float*)(ws + CST_OFF);
  float* xg = (float*)(ws + XG_OFF);

  // chunk T by available xg space
  size_t avail = (ws_size > XG_OFF) ? (ws_size - XG_OFF) : 0;
  long chunkT = (long)(avail / ((size_t)BB * GG * sizeof(float)));
  if (chunkT > TT) chunkT = TT;
  if (chunkT < 1) chunkT = 1;

  hipMemsetAsync(ws + EXCH_OFF, 0, 0x40000, stream);  // clear exchange tags
  for (int t0 = 0; t0 < TT; t0 += (int)chunkT) {
    int ct = (TT - t0 < chunkT) ? (TT - t0) : (int)chunkT;
    int mblk = (ct * BB + BM - 1) / BM;
    hipLaunchKernelGGL(lstm_xgates, dim3(mblk * (GG / BN)), dim3(256), 0, stream,
                       xin, Wih, bih, bhh, xg, t0, ct);
    hipLaunchKernelGGL(lstm_rec, dim3(256), dim3(256), 0, stream,
                       h0, c0, Whh, xg, out, exch, cstate, t0, t0 + ct);
  }
}